// Round 1
// baseline (114.777 us; speedup 1.0000x reference)
//
#include <hip/hip_runtime.h>

// out[b,k] = (WHT_2048(concat(x1[b],x2[b]))[k])^2 / 2048
// One wave (64 lanes) per row; 32 floats per lane.
// k = jo*256 + lane*4 + ji  (jo in [0,8), ji in [0,4))
//   k bits {0,1}   = ji   -> in-register stages (masks 1,2 on reg idx)
//   k bits {2..7}  = lane -> __shfl_xor stages (masks 1..32)
//   k bits {8,9,10}= jo   -> in-register stages (masks 4,8,16 on reg idx)

__global__ __launch_bounds__(256) void qf_wht_kernel(const float* __restrict__ x1,
                                                     const float* __restrict__ x2,
                                                     float* __restrict__ out,
                                                     int nrows) {
    const int wave = threadIdx.x >> 6;
    const int lane = threadIdx.x & 63;
    const int row  = blockIdx.x * 4 + wave;
    if (row >= nrows) return;

    float v[32];

    // ---- load: coalesced float4, first 4 chunks from x1, last 4 from x2 ----
    const float* __restrict__ p1 = x1 + (size_t)row * 1024 + lane * 4;
    const float* __restrict__ p2 = x2 + (size_t)row * 1024 + lane * 4;
#pragma unroll
    for (int jo = 0; jo < 4; ++jo) {
        float4 f = *(const float4*)(p1 + jo * 256);
        v[jo * 4 + 0] = f.x; v[jo * 4 + 1] = f.y;
        v[jo * 4 + 2] = f.z; v[jo * 4 + 3] = f.w;
    }
#pragma unroll
    for (int jo = 4; jo < 8; ++jo) {
        float4 f = *(const float4*)(p2 + (jo - 4) * 256);
        v[jo * 4 + 0] = f.x; v[jo * 4 + 1] = f.y;
        v[jo * 4 + 2] = f.z; v[jo * 4 + 3] = f.w;
    }

    // ---- 5 in-register WHT stages over the register index (k bits 0,1,8,9,10) ----
#pragma unroll
    for (int m = 1; m < 32; m <<= 1) {
#pragma unroll
        for (int j = 0; j < 32; ++j) {
            if ((j & m) == 0) {
                const float a = v[j];
                const float b = v[j | m];
                v[j]     = a + b;
                v[j | m] = a - b;
            }
        }
    }

    // ---- 6 cross-lane WHT stages over lane bits (k bits 2..7) ----
#pragma unroll
    for (int m = 1; m < 64; m <<= 1) {
        const float s = (lane & m) ? -1.0f : 1.0f;
#pragma unroll
        for (int j = 0; j < 32; ++j) {
            const float p = __shfl_xor(v[j], m, 64);
            v[j] = fmaf(s, v[j], p);   // lane-low: v+p ; lane-high: p-v
        }
    }

    // ---- square, scale by 1/2048, coalesced float4 stores ----
    const float scale = 1.0f / 2048.0f;
    float* __restrict__ po = out + (size_t)row * 2048 + lane * 4;
#pragma unroll
    for (int jo = 0; jo < 8; ++jo) {
        float4 f;
        f.x = v[jo * 4 + 0] * v[jo * 4 + 0] * scale;
        f.y = v[jo * 4 + 1] * v[jo * 4 + 1] * scale;
        f.z = v[jo * 4 + 2] * v[jo * 4 + 2] * scale;
        f.w = v[jo * 4 + 3] * v[jo * 4 + 3] * scale;
        *(float4*)(po + jo * 256) = f;
    }
}

extern "C" void kernel_launch(void* const* d_in, const int* in_sizes, int n_in,
                              void* d_out, int out_size, void* d_ws, size_t ws_size,
                              hipStream_t stream) {
    const float* x1 = (const float*)d_in[0];
    const float* x2 = (const float*)d_in[1];
    float* out = (float*)d_out;

    const int nrows = in_sizes[0] / 1024;           // 8192
    const int blocks = (nrows + 3) / 4;             // 4 rows per 256-thread block
    qf_wht_kernel<<<blocks, 256, 0, stream>>>(x1, x2, out, nrows);
}

// Round 2
// 111.672 us; speedup vs baseline: 1.0278x; 1.0278x over previous
//
#include <hip/hip_runtime.h>

// out[b,k] = (WHT_2048(concat(x1[b],x2[b]))[k])^2 / 2048
// One wave (64 lanes) per row; 32 floats per lane.
// k = jo*256 + lane*4 + ji  (jo in [0,8), ji in [0,4))
//   k bits {0,1}   = ji   -> in-register stages
//   k bits {2..7}  = lane -> cross-lane stages: DPP (xor1,2,4,8), swizzle (16), bpermute (32)
//   k bits {8,9,10}= jo   -> in-register stages

template <int CTRL>
__device__ __forceinline__ float dpp_xmov(float x) {
    return __int_as_float(__builtin_amdgcn_update_dpp(
        0, __float_as_int(x), CTRL, 0xF, 0xF, true));
}

__global__ __launch_bounds__(256) void qf_wht_kernel(const float* __restrict__ x1,
                                                     const float* __restrict__ x2,
                                                     float* __restrict__ out,
                                                     int nrows) {
    const int wave = threadIdx.x >> 6;
    const int lane = threadIdx.x & 63;
    const int row  = blockIdx.x * 4 + wave;
    if (row >= nrows) return;

    float v[32];

    // ---- load: coalesced float4 ----
    const float* __restrict__ p1 = x1 + (size_t)row * 1024 + lane * 4;
    const float* __restrict__ p2 = x2 + (size_t)row * 1024 + lane * 4;
#pragma unroll
    for (int jo = 0; jo < 4; ++jo) {
        float4 f = *(const float4*)(p1 + jo * 256);
        v[jo * 4 + 0] = f.x; v[jo * 4 + 1] = f.y;
        v[jo * 4 + 2] = f.z; v[jo * 4 + 3] = f.w;
    }
#pragma unroll
    for (int jo = 4; jo < 8; ++jo) {
        float4 f = *(const float4*)(p2 + (jo - 4) * 256);
        v[jo * 4 + 0] = f.x; v[jo * 4 + 1] = f.y;
        v[jo * 4 + 2] = f.z; v[jo * 4 + 3] = f.w;
    }

    // ---- 5 in-register stages (k bits 0,1,8,9,10) ----
#pragma unroll
    for (int m = 1; m < 32; m <<= 1) {
#pragma unroll
        for (int j = 0; j < 32; ++j) {
            if ((j & m) == 0) {
                const float a = v[j];
                const float b = v[j | m];
                v[j]     = a + b;
                v[j | m] = a - b;
            }
        }
    }

    // ---- cross-lane stages (k bits 2..7), partner p: v' = s*v + p ----
    // xor1: quad_perm [1,0,3,2] = 0xB1  (VALU/DPP)
    {
        const float s = (lane & 1) ? -1.0f : 1.0f;
#pragma unroll
        for (int j = 0; j < 32; ++j) {
            const float p = dpp_xmov<0xB1>(v[j]);
            v[j] = fmaf(s, v[j], p);
        }
    }
    // xor2: quad_perm [2,3,0,1] = 0x4E  (VALU/DPP)
    {
        const float s = (lane & 2) ? -1.0f : 1.0f;
#pragma unroll
        for (int j = 0; j < 32; ++j) {
            const float p = dpp_xmov<0x4E>(v[j]);
            v[j] = fmaf(s, v[j], p);
        }
    }
    // xor4 = xor3 (quad_perm [3,2,1,0] = 0x1B) ∘ xor7 (row_half_mirror = 0x141)
    {
        const float s = (lane & 4) ? -1.0f : 1.0f;
#pragma unroll
        for (int j = 0; j < 32; ++j) {
            const float p = dpp_xmov<0x141>(dpp_xmov<0x1B>(v[j]));
            v[j] = fmaf(s, v[j], p);
        }
    }
    // xor8 = xor7 (row_half_mirror = 0x141) ∘ xor15 (row_mirror = 0x140)
    {
        const float s = (lane & 8) ? -1.0f : 1.0f;
#pragma unroll
        for (int j = 0; j < 32; ++j) {
            const float p = dpp_xmov<0x140>(dpp_xmov<0x141>(v[j]));
            v[j] = fmaf(s, v[j], p);
        }
    }
    // xor16: ds_swizzle BitMode xor_mask=16 -> offset 0x401F (LDS pipe, no index reg)
    {
        const float s = (lane & 16) ? -1.0f : 1.0f;
#pragma unroll
        for (int j = 0; j < 32; ++j) {
            const float p = __int_as_float(
                __builtin_amdgcn_ds_swizzle(__float_as_int(v[j]), 0x401F));
            v[j] = fmaf(s, v[j], p);
        }
    }
    // xor32: full-wave ds_bpermute with precomputed byte index
    {
        const float s = (lane & 32) ? -1.0f : 1.0f;
        const int idx32 = (lane ^ 32) << 2;
#pragma unroll
        for (int j = 0; j < 32; ++j) {
            const float p = __int_as_float(
                __builtin_amdgcn_ds_bpermute(idx32, __float_as_int(v[j])));
            v[j] = fmaf(s, v[j], p);
        }
    }

    // ---- square, scale, coalesced float4 stores ----
    const float scale = 1.0f / 2048.0f;
    float* __restrict__ po = out + (size_t)row * 2048 + lane * 4;
#pragma unroll
    for (int jo = 0; jo < 8; ++jo) {
        float4 f;
        f.x = v[jo * 4 + 0] * v[jo * 4 + 0] * scale;
        f.y = v[jo * 4 + 1] * v[jo * 4 + 1] * scale;
        f.z = v[jo * 4 + 2] * v[jo * 4 + 2] * scale;
        f.w = v[jo * 4 + 3] * v[jo * 4 + 3] * scale;
        *(float4*)(po + jo * 256) = f;
    }
}

extern "C" void kernel_launch(void* const* d_in, const int* in_sizes, int n_in,
                              void* d_out, int out_size, void* d_ws, size_t ws_size,
                              hipStream_t stream) {
    const float* x1 = (const float*)d_in[0];
    const float* x2 = (const float*)d_in[1];
    float* out = (float*)d_out;

    const int nrows = in_sizes[0] / 1024;           // 8192
    const int blocks = (nrows + 3) / 4;             // 4 rows per 256-thread block
    qf_wht_kernel<<<blocks, 256, 0, stream>>>(x1, x2, out, nrows);
}